// Round 1
// baseline (161.852 us; speedup 1.0000x reference)
//
#include <hip/hip_runtime.h>
#include <stdint.h>

typedef float  f32x2 __attribute__((ext_vector_type(2)));
typedef float  f32x4 __attribute__((ext_vector_type(4)));
typedef short  s16x8 __attribute__((ext_vector_type(8)));
typedef unsigned short u16;

#define GN_EPS 1e-5f

// Problem constants: x[256][256][256] f32, y: 1024 x (128*128), w: [512][1024], out [512][16384]
// ws layout (bytes):
//   0       gsum[128] f32
//   512     gsqs[128] f32
//   1024    ac[1024]  f32
//   5120    bc[1024]  f32
//   9216    tvec[512] f32
//   16384   wn[512*1024] bf16 (1 MiB)
//   2097152 yt[16384*1024] bf16 (32 MiB)   -- y transposed: [hw][c]

__device__ __forceinline__ u16 f2bf(float f) {
  unsigned u = __float_as_uint(f);
  u += 0x7fffu + ((u >> 16) & 1u);
  return (u16)(u >> 16);
}

__device__ __forceinline__ float wave_red_sum(float v) {
#pragma unroll
  for (int off = 32; off > 0; off >>= 1) v += __shfl_down(v, off, 64);
  return v;
}

__device__ __forceinline__ void gload16(const void* g, void* l) {
  __builtin_amdgcn_global_load_lds(
      (const __attribute__((address_space(1))) uint32_t*)(uintptr_t)g,
      (__attribute__((address_space(3))) uint32_t*)(uintptr_t)l,
      16, 0, 0);
}

// ---------------- Phase A: Haar + y_t(bf16) + group partial stats ----------------
// grid (64, 32): blockIdx.x = hw tile (256 positions), blockIdx.y = channel-group cg (8 channels)
__global__ __launch_bounds__(256) void haar_kernel(
    const float* __restrict__ x, u16* __restrict__ yt,
    float* __restrict__ gsum, float* __restrict__ gsqs)
{
  const int t  = threadIdx.x;
  const int cg = blockIdx.y;                 // 0..31
  const int hw = blockIdx.x * 256 + t;       // 0..16383
  const int h  = hw >> 7, w = hw & 127;
  const int c0 = cg << 3;

  float s[4] = {0.f,0.f,0.f,0.f}, q[4] = {0.f,0.f,0.f,0.f};
  s16x8 ov[4];

  const float* xb = x + (size_t)(2*h) * 256 + (size_t)(2*w);
#pragma unroll
  for (int j = 0; j < 8; ++j) {
    const float* xp = xb + ((size_t)(c0 + j) << 16);
    f32x2 r0 = *(const f32x2*)(xp);
    f32x2 r1 = *(const f32x2*)(xp + 256);
    float x00 = r0.x, x01 = r0.y, x10 = r1.x, x11 = r1.y;
    float LL = 0.5f*( x00 + x01 + x10 + x11);
    float HL = 0.5f*(-x00 - x01 + x10 + x11);
    float LH = 0.5f*(-x00 + x01 - x10 + x11);
    float HH = 0.5f*( x00 - x01 - x10 + x11);
    ov[0][j] = (short)f2bf(LL);
    ov[1][j] = (short)f2bf(HL);
    ov[2][j] = (short)f2bf(LH);
    ov[3][j] = (short)f2bf(HH);
    s[0] += LL; q[0] += LL*LL;
    s[1] += HL; q[1] += HL*HL;
    s[2] += LH; q[2] += LH*LH;
    s[3] += HH; q[3] += HH*HH;
  }
  u16* yb = yt + (size_t)hw * 1024 + c0;
#pragma unroll
  for (int b = 0; b < 4; ++b)
    *(s16x8*)(yb + b*256) = ov[b];

  // block-reduce 8 scalars (4 sums, 4 sumsq) -> 8 atomics per block
  __shared__ float red[4][8];
  const int lane = t & 63, wv = t >> 6;
  float r[8];
#pragma unroll
  for (int j = 0; j < 8; ++j) r[j] = wave_red_sum(j < 4 ? s[j] : q[j-4]);
  if (lane == 0) {
#pragma unroll
    for (int j = 0; j < 8; ++j) red[wv][j] = r[j];
  }
  __syncthreads();
  if (t < 8) {
    float tot = red[0][t] + red[1][t] + red[2][t] + red[3][t];
    int b = t & 3;
    if (t < 4) atomicAdd(&gsum[b*32 + cg], tot);
    else       atomicAdd(&gsqs[b*32 + cg], tot);
  }
}

// ---------------- Phase B1: per-channel affine coefs ----------------
__global__ void stats_kernel(const float* __restrict__ gsum, const float* __restrict__ gsqs,
                             const float* __restrict__ scale, const float* __restrict__ bias,
                             float* __restrict__ ac, float* __restrict__ bc)
{
  int c = blockIdx.x * 256 + threadIdx.x;
  if (c >= 1024) return;
  int g = c >> 3;
  const float invN = 1.0f / 131072.0f;
  float mean = gsum[g] * invN;
  float var  = gsqs[g] * invN - mean * mean;
  float inv  = rsqrtf(var + GN_EPS);
  float a = scale[c] * inv;
  ac[c] = a;
  bc[c] = bias[c] - mean * a;
}

// ---------------- Phase B2: fold a_c into weights (bf16) + bias vector t ----------------
__global__ __launch_bounds__(256) void wprep_kernel(
    const float* __restrict__ wproj, const float* __restrict__ ac,
    const float* __restrict__ bc, u16* __restrict__ wn, float* __restrict__ tvec)
{
  const int o = blockIdx.x;     // 0..511
  const int t = threadIdx.x;
  float acc = 0.f;
#pragma unroll
  for (int j = 0; j < 4; ++j) {
    int c = j*256 + t;
    float wv = wproj[o*1024 + c];
    wn[o*1024 + c] = f2bf(wv * ac[c]);
    acc += wv * bc[c];
  }
  acc = wave_red_sum(acc);
  __shared__ float red[4];
  int lane = t & 63, wvi = t >> 6;
  if (lane == 0) red[wvi] = acc;
  __syncthreads();
  if (t == 0) tvec[o] = red[0] + red[1] + red[2] + red[3];
}

// ---------------- Phase C: GEMM out[o][hw] = relu(sum_c wn[o][c]*yt[hw][c] + t[o]) ----------------
#define BM 128
#define BN 128
#define BK 64

__global__ __launch_bounds__(256) void gemm_kernel(
    const u16* __restrict__ A,   // wn [512][1024]  row-major, K contiguous
    const u16* __restrict__ B,   // yt [16384][1024] row-major, K contiguous
    const float* __restrict__ tvec,
    float* __restrict__ out)     // [512][16384]
{
  __shared__ __align__(1024) u16 As[BM*BK];  // 16 KiB, [128 rows][128 B], XOR-swizzled
  __shared__ __align__(1024) u16 Bs[BN*BK];  // 16 KiB

  const int tid  = threadIdx.x;
  const int lane = tid & 63, wave = tid >> 6;
  const int m0 = blockIdx.y * BM;
  const int n0 = blockIdx.x * BN;
  const int wm = wave >> 1, wn_ = wave & 1;  // 2x2 waves of 64x64
  const int g = lane >> 4, r = lane & 15;

  f32x4 acc[4][4];
#pragma unroll
  for (int i = 0; i < 4; ++i)
#pragma unroll
    for (int j = 0; j < 4; ++j) acc[i][j] = (f32x4)(0.f);

  for (int k0 = 0; k0 < 1024; k0 += BK) {
    // ---- stage both tiles: 16 chunks of 1 KiB each, 4 per wave per operand ----
#pragma unroll
    for (int ci = 0; ci < 4; ++ci) {
      int chunk  = wave*4 + ci;
      int linear = chunk*1024 + lane*16;      // byte position in the 16 KiB tile
      int row    = linear >> 7;               // 128 B per row (64 bf16)
      int sb     = linear & 127;
      int so     = sb ^ ((row & 7) << 4);     // inverse-swizzled source slot
      gload16((const char*)(A + (size_t)(m0 + row)*1024 + k0) + so,
              (char*)As + chunk*1024);
      gload16((const char*)(B + (size_t)(n0 + row)*1024 + k0) + so,
              (char*)Bs + chunk*1024);
    }
    __syncthreads();

    // ---- compute: 2 k-halves x (4+4 ds_read_b128 + 16 MFMA) per wave ----
#pragma unroll
    for (int kk = 0; kk < 2; ++kk) {
      s16x8 av[4], bv[4];
      const int kb = g*16 + kk*64;
#pragma unroll
      for (int m = 0; m < 4; ++m) {
        int row = wm*64 + m*16 + r;
        av[m] = *(const s16x8*)((const char*)As + row*128 + (kb ^ ((row & 7) << 4)));
      }
#pragma unroll
      for (int n = 0; n < 4; ++n) {
        int row = wn_*64 + n*16 + r;
        bv[n] = *(const s16x8*)((const char*)Bs + row*128 + (kb ^ ((row & 7) << 4)));
      }
#pragma unroll
      for (int m = 0; m < 4; ++m)
#pragma unroll
        for (int n = 0; n < 4; ++n)
          acc[m][n] = __builtin_amdgcn_mfma_f32_16x16x32_bf16(av[m], bv[n], acc[m][n], 0, 0, 0);
    }
    __syncthreads();
  }

  // ---- epilogue: +bias, ReLU, store ----
#pragma unroll
  for (int m = 0; m < 4; ++m) {
#pragma unroll
    for (int rr = 0; rr < 4; ++rr) {
      int o = m0 + wm*64 + m*16 + g*4 + rr;
      float tv = tvec[o];
      float* op = out + (size_t)o*16384 + n0 + wn_*64 + r;
#pragma unroll
      for (int n = 0; n < 4; ++n) {
        float v = acc[m][n][rr] + tv;
        op[n*16] = v > 0.f ? v : 0.f;
      }
    }
  }
}

extern "C" void kernel_launch(void* const* d_in, const int* in_sizes, int n_in,
                              void* d_out, int out_size, void* d_ws, size_t ws_size,
                              hipStream_t stream)
{
  const float* x  = (const float*)d_in[0];
  const float* sc = (const float*)d_in[1];
  const float* bi = (const float*)d_in[2];
  const float* wp = (const float*)d_in[3];
  float* out = (float*)d_out;

  char* ws = (char*)d_ws;
  float* gsum = (float*)(ws + 0);
  float* gsqs = (float*)(ws + 512);
  float* ac   = (float*)(ws + 1024);
  float* bc   = (float*)(ws + 5120);
  float* tv   = (float*)(ws + 9216);
  u16*   wn   = (u16*)(ws + 16384);
  u16*   yt   = (u16*)(ws + 2097152);

  hipMemsetAsync(ws, 0, 1024, stream);  // zero gsum+gsqs (ws is poisoned each call)
  hipLaunchKernelGGL(haar_kernel,  dim3(64, 32), dim3(256), 0, stream, x, yt, gsum, gsqs);
  hipLaunchKernelGGL(stats_kernel, dim3(4),      dim3(256), 0, stream, gsum, gsqs, sc, bi, ac, bc);
  hipLaunchKernelGGL(wprep_kernel, dim3(512),    dim3(256), 0, stream, wp, ac, bc, wn, tv);
  hipLaunchKernelGGL(gemm_kernel,  dim3(128, 4), dim3(256), 0, stream, wn, yt, tv, out);
}

// Round 2
// 142.136 us; speedup vs baseline: 1.1387x; 1.1387x over previous
//
#include <hip/hip_runtime.h>
#include <stdint.h>

typedef float  f32x2 __attribute__((ext_vector_type(2)));
typedef float  f32x4 __attribute__((ext_vector_type(4)));
typedef short  s16x8 __attribute__((ext_vector_type(8)));
typedef unsigned short u16;

#define GN_EPS 1e-5f

// Problem constants: x[256][256][256] f32, y: 1024 x (128*128), w: [512][1024], out [512][16384]
// ws layout (bytes):
//   0       gsum[128] f32
//   512     gsqs[128] f32
//   9216    tvec[512] f32
//   16384   wn[512*1024] bf16 (1 MiB)
//   2097152 yt[16384*1024] bf16 (32 MiB)   -- y transposed: [hw][c]

__device__ __forceinline__ u16 f2bf(float f) {
  unsigned u = __float_as_uint(f);
  u += 0x7fffu + ((u >> 16) & 1u);
  return (u16)(u >> 16);
}

__device__ __forceinline__ float wave_red_sum(float v) {
#pragma unroll
  for (int off = 32; off > 0; off >>= 1) v += __shfl_down(v, off, 64);
  return v;
}

__device__ __forceinline__ void gload16(const void* g, void* l) {
  __builtin_amdgcn_global_load_lds(
      (const __attribute__((address_space(1))) uint32_t*)(uintptr_t)g,
      (__attribute__((address_space(3))) uint32_t*)(uintptr_t)l,
      16, 0, 0);
}

// ---------------- Phase A: Haar + y_t(bf16) + group partial stats ----------------
// grid (256, 4), block 256.
// blockIdx.x: tile of 64 consecutive hw (within one h row); blockIdx.y: 64 input channels.
// Lane layout: cti = t&7 (channel sub-group of 8), hwi = t>>3 (hw pair).
// Store instr: 8 consecutive lanes (cti 0..7) write 128 B fully contiguous -> full lines.
__global__ __launch_bounds__(256) void haar_kernel(
    const float* __restrict__ x, u16* __restrict__ yt,
    float* __restrict__ gsum, float* __restrict__ gsqs)
{
  const int t    = threadIdx.x;
  const int cti  = t & 7;
  const int hwi  = t >> 3;                      // 0..31
  const int hw0  = blockIdx.x * 64 + hwi * 2;   // even hw; pair {hw0, hw0+1}
  const int h    = hw0 >> 7, w = hw0 & 127;     // w, w+1 in same row (w even)
  const int cin0 = blockIdx.y * 64 + cti * 8;   // 8 input channels

  float sv[4] = {0.f,0.f,0.f,0.f}, qv[4] = {0.f,0.f,0.f,0.f};
  s16x8 ov[2][4];

  const float* xb = x + ((size_t)cin0 << 16) + (size_t)(2*h)*256 + (size_t)(2*w);
#pragma unroll
  for (int j = 0; j < 8; ++j) {
    const float* xp = xb + ((size_t)j << 16);
    f32x4 r0 = *(const f32x4*)(xp);        // x[c][2h][2w..2w+3]
    f32x4 r1 = *(const f32x4*)(xp + 256);  // x[c][2h+1][2w..2w+3]
#pragma unroll
    for (int p = 0; p < 2; ++p) {
      float x00 = p ? r0.z : r0.x;
      float x01 = p ? r0.w : r0.y;
      float x10 = p ? r1.z : r1.x;
      float x11 = p ? r1.w : r1.y;
      float LL = 0.5f*( x00 + x01 + x10 + x11);
      float HL = 0.5f*(-x00 - x01 + x10 + x11);
      float LH = 0.5f*(-x00 + x01 - x10 + x11);
      float HH = 0.5f*( x00 - x01 - x10 + x11);
      ov[p][0][j] = (short)f2bf(LL);
      ov[p][1][j] = (short)f2bf(HL);
      ov[p][2][j] = (short)f2bf(LH);
      ov[p][3][j] = (short)f2bf(HH);
      sv[0] += LL; qv[0] += LL*LL;
      sv[1] += HL; qv[1] += HL*HL;
      sv[2] += LH; qv[2] += LH*LH;
      sv[3] += HH; qv[3] += HH*HH;
    }
  }

  u16* yb = yt + (size_t)hw0 * 1024 + cin0;
#pragma unroll
  for (int p = 0; p < 2; ++p)
#pragma unroll
    for (int b = 0; b < 4; ++b)
      *(s16x8*)(yb + p*1024 + b*256) = ov[p][b];

  // ---- stats: thread's sv[b]/qv[b] is partial sum of group g = b*32 + by*8 + cti ----
  // reduce across hwi lanes within wave (xor 8/16/32), then across 4 waves via LDS.
#pragma unroll
  for (int k = 0; k < 4; ++k) {
#pragma unroll
    for (int msk = 8; msk < 64; msk <<= 1) {
      sv[k] += __shfl_xor(sv[k], msk, 64);
      qv[k] += __shfl_xor(qv[k], msk, 64);
    }
  }
  __shared__ float red[4][8][8];
  const int lane = t & 63, wv = t >> 6;
  if (lane < 8) {
#pragma unroll
    for (int k = 0; k < 4; ++k) {
      red[wv][lane][k]     = sv[k];
      red[wv][lane][4 + k] = qv[k];
    }
  }
  __syncthreads();
  if (t < 64) {
    int c8 = t & 7, vi = t >> 3;                 // vi: 0..3 sums, 4..7 sumsq
    float tot = red[0][c8][vi] + red[1][c8][vi] + red[2][c8][vi] + red[3][c8][vi];
    int b = vi & 3;
    int g = b*32 + blockIdx.y*8 + c8;
    if (vi < 4) atomicAdd(&gsum[g], tot);
    else        atomicAdd(&gsqs[g], tot);
  }
}

// ---------------- Phase B: stats + fold a_c into weights (bf16) + bias vector t ----------------
__global__ __launch_bounds__(256) void wprep_kernel(
    const float* __restrict__ wproj, const float* __restrict__ gsum,
    const float* __restrict__ gsqs, const float* __restrict__ scale,
    const float* __restrict__ bias, u16* __restrict__ wn, float* __restrict__ tvec)
{
  const int o = blockIdx.x;     // 0..511
  const int t = threadIdx.x;
  const float invN = 1.0f / 131072.0f;
  float acc = 0.f;
#pragma unroll
  for (int j = 0; j < 4; ++j) {
    int c = j*256 + t;
    int g = c >> 3;
    float mean = gsum[g] * invN;
    float var  = gsqs[g] * invN - mean * mean;
    float inv  = rsqrtf(var + GN_EPS);
    float a = scale[c] * inv;
    float b = bias[c] - mean * a;
    float wv = wproj[o*1024 + c];
    wn[o*1024 + c] = f2bf(wv * a);
    acc += wv * b;
  }
  acc = wave_red_sum(acc);
  __shared__ float red[4];
  int lane = t & 63, wvi = t >> 6;
  if (lane == 0) red[wvi] = acc;
  __syncthreads();
  if (t == 0) tvec[o] = red[0] + red[1] + red[2] + red[3];
}

// ---------------- Phase C: GEMM out[o][hw] = relu(sum_c wn[o][c]*yt[hw][c] + t[o]) ----------------
#define BM 128
#define BN 128
#define BK 64

__global__ __launch_bounds__(256) void gemm_kernel(
    const u16* __restrict__ A,   // wn [512][1024]  row-major, K contiguous
    const u16* __restrict__ B,   // yt [16384][1024] row-major, K contiguous
    const float* __restrict__ tvec,
    float* __restrict__ out)     // [512][16384]
{
  __shared__ __align__(1024) u16 As[BM*BK];  // 16 KiB, [128 rows][128 B], XOR-swizzled
  __shared__ __align__(1024) u16 Bs[BN*BK];  // 16 KiB

  const int tid  = threadIdx.x;
  const int lane = tid & 63, wave = tid >> 6;

  // XCD-chunked, m-fast swizzle: each XCD owns 16 consecutive n-panels (4 MB of B = its L2)
  const int bid = blockIdx.x;                // 0..511
  const int cid = (bid & 7) * 64 + (bid >> 3);
  const int m0 = (cid & 3) * BM;
  const int n0 = (cid >> 2) * BN;

  const int wm = wave >> 1, wn_ = wave & 1;  // 2x2 waves of 64x64
  const int g = lane >> 4, r = lane & 15;

  f32x4 acc[4][4];
#pragma unroll
  for (int i = 0; i < 4; ++i)
#pragma unroll
    for (int j = 0; j < 4; ++j) acc[i][j] = (f32x4)(0.f);

  for (int k0 = 0; k0 < 1024; k0 += BK) {
    // ---- stage both tiles: 16 chunks of 1 KiB each, 4 per wave per operand ----
#pragma unroll
    for (int ci = 0; ci < 4; ++ci) {
      int chunk  = wave*4 + ci;
      int linear = chunk*1024 + lane*16;      // byte position in the 16 KiB tile
      int row    = linear >> 7;               // 128 B per row (64 bf16)
      int sb     = linear & 127;
      int so     = sb ^ ((row & 7) << 4);     // inverse-swizzled source slot
      gload16((const char*)(A + (size_t)(m0 + row)*1024 + k0) + so,
              (char*)As + chunk*1024);
      gload16((const char*)(B + (size_t)(n0 + row)*1024 + k0) + so,
              (char*)Bs + chunk*1024);
    }
    __syncthreads();

    // ---- compute: 2 k-halves x (4+4 ds_read_b128 + 16 MFMA) per wave ----
#pragma unroll
    for (int kk = 0; kk < 2; ++kk) {
      s16x8 av[4], bv[4];
      const int kb = g*16 + kk*64;
#pragma unroll
      for (int m = 0; m < 4; ++m) {
        int row = wm*64 + m*16 + r;
        av[m] = *(const s16x8*)((const char*)As + row*128 + (kb ^ ((row & 7) << 4)));
      }
#pragma unroll
      for (int n = 0; n < 4; ++n) {
        int row = wn_*64 + n*16 + r;
        bv[n] = *(const s16x8*)((const char*)Bs + row*128 + (kb ^ ((row & 7) << 4)));
      }
#pragma unroll
      for (int m = 0; m < 4; ++m)
#pragma unroll
        for (int n = 0; n < 4; ++n)
          acc[m][n] = __builtin_amdgcn_mfma_f32_16x16x32_bf16(av[m], bv[n], acc[m][n], 0, 0, 0);
    }
    __syncthreads();
  }

  // ---- epilogue: +bias, ReLU, store ----
#pragma unroll
  for (int m = 0; m < 4; ++m) {
#pragma unroll
    for (int rr = 0; rr < 4; ++rr) {
      int o = m0 + wm*64 + m*16 + g*4 + rr;
      float tv = tvec[o];
      float* op = out + (size_t)o*16384 + n0 + wn_*64 + r;
#pragma unroll
      for (int n = 0; n < 4; ++n) {
        float v = acc[m][n][rr] + tv;
        op[n*16] = v > 0.f ? v : 0.f;
      }
    }
  }
}

extern "C" void kernel_launch(void* const* d_in, const int* in_sizes, int n_in,
                              void* d_out, int out_size, void* d_ws, size_t ws_size,
                              hipStream_t stream)
{
  const float* x  = (const float*)d_in[0];
  const float* sc = (const float*)d_in[1];
  const float* bi = (const float*)d_in[2];
  const float* wp = (const float*)d_in[3];
  float* out = (float*)d_out;

  char* ws = (char*)d_ws;
  float* gsum = (float*)(ws + 0);
  float* gsqs = (float*)(ws + 512);
  float* tv   = (float*)(ws + 9216);
  u16*   wn   = (u16*)(ws + 16384);
  u16*   yt   = (u16*)(ws + 2097152);

  hipMemsetAsync(ws, 0, 1024, stream);  // zero gsum+gsqs (ws is poisoned each call)
  hipLaunchKernelGGL(haar_kernel,  dim3(256, 4), dim3(256), 0, stream, x, yt, gsum, gsqs);
  hipLaunchKernelGGL(wprep_kernel, dim3(512),    dim3(256), 0, stream, wp, gsum, gsqs, sc, bi, wn, tv);
  hipLaunchKernelGGL(gemm_kernel,  dim3(512),    dim3(256), 0, stream, wn, yt, tv, out);
}

// Round 4
// 138.692 us; speedup vs baseline: 1.1670x; 1.0248x over previous
//
#include <hip/hip_runtime.h>
#include <stdint.h>

typedef float  f32x2 __attribute__((ext_vector_type(2)));
typedef float  f32x4 __attribute__((ext_vector_type(4)));
typedef short  s16x8 __attribute__((ext_vector_type(8)));
typedef unsigned short u16;

#define GN_EPS 1e-5f

// Problem constants: x[256][256][256] f32, y: 1024 x (128*128), w: [512][1024], out [512][16384]
// ws layout (bytes):
//   0       gsum[128] f32
//   512     gsqs[128] f32
//   9216    tvec[512] f32
//   16384   wn[512*1024] bf16 (1 MiB)
//   2097152 yt[16384*1024] bf16 (32 MiB)   -- y transposed: [hw][c]

__device__ __forceinline__ u16 f2bf(float f) {
  unsigned u = __float_as_uint(f);
  u += 0x7fffu + ((u >> 16) & 1u);
  return (u16)(u >> 16);
}

__device__ __forceinline__ float wave_red_sum(float v) {
#pragma unroll
  for (int off = 32; off > 0; off >>= 1) v += __shfl_down(v, off, 64);
  return v;
}

__device__ __forceinline__ void gload16(const void* g, void* l) {
  __builtin_amdgcn_global_load_lds(
      (const __attribute__((address_space(1))) uint32_t*)(uintptr_t)g,
      (__attribute__((address_space(3))) uint32_t*)(uintptr_t)l,
      16, 0, 0);
}

// ---------------- Phase A: Haar + y_t(bf16) + group partial stats ----------------
// grid (256, 4), block 256.
// blockIdx.x: tile of 64 consecutive hw (within one h row); blockIdx.y: 64 input channels.
// Lane layout: cti = t&7 (channel sub-group of 8), hwi = t>>3 (hw pair).
// Store instr: 8 consecutive lanes (cti 0..7) write 128 B fully contiguous -> full lines.
__global__ __launch_bounds__(256) void haar_kernel(
    const float* __restrict__ x, u16* __restrict__ yt,
    float* __restrict__ gsum, float* __restrict__ gsqs)
{
  const int t    = threadIdx.x;
  const int cti  = t & 7;
  const int hwi  = t >> 3;                      // 0..31
  const int hw0  = blockIdx.x * 64 + hwi * 2;   // even hw; pair {hw0, hw0+1}
  const int h    = hw0 >> 7, w = hw0 & 127;     // w, w+1 in same row (w even)
  const int cin0 = blockIdx.y * 64 + cti * 8;   // 8 input channels

  float sv[4] = {0.f,0.f,0.f,0.f}, qv[4] = {0.f,0.f,0.f,0.f};
  s16x8 ov[2][4];

  const float* xb = x + ((size_t)cin0 << 16) + (size_t)(2*h)*256 + (size_t)(2*w);
#pragma unroll
  for (int j = 0; j < 8; ++j) {
    const float* xp = xb + ((size_t)j << 16);
    f32x4 r0 = *(const f32x4*)(xp);        // x[c][2h][2w..2w+3]
    f32x4 r1 = *(const f32x4*)(xp + 256);  // x[c][2h+1][2w..2w+3]
#pragma unroll
    for (int p = 0; p < 2; ++p) {
      float x00 = p ? r0.z : r0.x;
      float x01 = p ? r0.w : r0.y;
      float x10 = p ? r1.z : r1.x;
      float x11 = p ? r1.w : r1.y;
      float LL = 0.5f*( x00 + x01 + x10 + x11);
      float HL = 0.5f*(-x00 - x01 + x10 + x11);
      float LH = 0.5f*(-x00 + x01 - x10 + x11);
      float HH = 0.5f*( x00 - x01 - x10 + x11);
      ov[p][0][j] = (short)f2bf(LL);
      ov[p][1][j] = (short)f2bf(HL);
      ov[p][2][j] = (short)f2bf(LH);
      ov[p][3][j] = (short)f2bf(HH);
      sv[0] += LL; qv[0] += LL*LL;
      sv[1] += HL; qv[1] += HL*HL;
      sv[2] += LH; qv[2] += LH*LH;
      sv[3] += HH; qv[3] += HH*HH;
    }
  }

  u16* yb = yt + (size_t)hw0 * 1024 + cin0;
#pragma unroll
  for (int p = 0; p < 2; ++p)
#pragma unroll
    for (int b = 0; b < 4; ++b)
      *(s16x8*)(yb + p*1024 + b*256) = ov[p][b];

  // ---- stats: thread's sv[b]/qv[b] is partial sum of group g = b*32 + by*8 + cti ----
#pragma unroll
  for (int k = 0; k < 4; ++k) {
#pragma unroll
    for (int msk = 8; msk < 64; msk <<= 1) {
      sv[k] += __shfl_xor(sv[k], msk, 64);
      qv[k] += __shfl_xor(qv[k], msk, 64);
    }
  }
  __shared__ float red[4][8][8];
  const int lane = t & 63, wv = t >> 6;
  if (lane < 8) {
#pragma unroll
    for (int k = 0; k < 4; ++k) {
      red[wv][lane][k]     = sv[k];
      red[wv][lane][4 + k] = qv[k];
    }
  }
  __syncthreads();
  if (t < 64) {
    int c8 = t & 7, vi = t >> 3;                 // vi: 0..3 sums, 4..7 sumsq
    float tot = red[0][c8][vi] + red[1][c8][vi] + red[2][c8][vi] + red[3][c8][vi];
    int b = vi & 3;
    int g = b*32 + blockIdx.y*8 + c8;
    if (vi < 4) atomicAdd(&gsum[g], tot);
    else        atomicAdd(&gsqs[g], tot);
  }
}

// ---------------- Phase B: stats + fold a_c into weights (bf16) + bias vector t ----------------
__global__ __launch_bounds__(256) void wprep_kernel(
    const float* __restrict__ wproj, const float* __restrict__ gsum,
    const float* __restrict__ gsqs, const float* __restrict__ scale,
    const float* __restrict__ bias, u16* __restrict__ wn, float* __restrict__ tvec)
{
  const int o = blockIdx.x;     // 0..511
  const int t = threadIdx.x;
  const float invN = 1.0f / 131072.0f;
  float acc = 0.f;
#pragma unroll
  for (int j = 0; j < 4; ++j) {
    int c = j*256 + t;
    int g = c >> 3;
    float mean = gsum[g] * invN;
    float var  = gsqs[g] * invN - mean * mean;
    float inv  = rsqrtf(var + GN_EPS);
    float a = scale[c] * inv;
    float b = bias[c] - mean * a;
    float wv = wproj[o*1024 + c];
    wn[o*1024 + c] = f2bf(wv * a);
    acc += wv * b;
  }
  acc = wave_red_sum(acc);
  __shared__ float red[4];
  int lane = t & 63, wvi = t >> 6;
  if (lane == 0) red[wvi] = acc;
  __syncthreads();
  if (t == 0) tvec[o] = red[0] + red[1] + red[2] + red[3];
}

// ---------------- Phase C: GEMM out[o][hw] = relu(sum_c wn[o][c]*yt[hw][c] + t[o]) ----------------
// 2-phase pipelined (T3 minimum): LDS double-buffer, STAGE(next) issued BEFORE
// ds_read+MFMA(cur), single vmcnt(0)+barrier per K-step (inside __syncthreads).
#define BM 128
#define BN 128
#define BK 64

__global__ __launch_bounds__(256) void gemm_kernel(
    const u16* __restrict__ A,   // wn [512][1024]  row-major, K contiguous
    const u16* __restrict__ B,   // yt [16384][1024] row-major, K contiguous
    const float* __restrict__ tvec,
    float* __restrict__ out)     // [512][16384]
{
  __shared__ __align__(1024) u16 As[2][BM*BK];  // 2 x 16 KiB, XOR-swizzled rows
  __shared__ __align__(1024) u16 Bs[2][BN*BK];

  const int tid  = threadIdx.x;
  const int lane = tid & 63, wave = tid >> 6;

  // XCD-chunked, m-fast swizzle: each XCD owns 16 consecutive n-panels (4 MB of B = its L2)
  const int bid = blockIdx.x;                // 0..511
  const int cid = (bid & 7) * 64 + (bid >> 3);
  const int m0 = (cid & 3) * BM;
  const int n0 = (cid >> 2) * BN;

  const int wm = wave >> 1, wn_ = wave & 1;  // 2x2 waves of 64x64
  const int g = lane >> 4, r = lane & 15;

  f32x4 acc[4][4];
#pragma unroll
  for (int i = 0; i < 4; ++i)
#pragma unroll
    for (int j = 0; j < 4; ++j) acc[i][j] = (f32x4)(0.f);

  // per-thread staging geometry (wave-uniform LDS base + lane*16, source pre-inverse-swizzled)
  const int chunk0 = wave * 4;
  int srow[4], soff[4];
#pragma unroll
  for (int ci = 0; ci < 4; ++ci) {
    int linear = (chunk0 + ci) * 1024 + lane * 16;
    srow[ci] = linear >> 7;
    soff[ci] = (linear & 127) ^ ((srow[ci] & 7) << 4);
  }

  auto STAGE = [&](int buf, int k0) {
#pragma unroll
    for (int ci = 0; ci < 4; ++ci) {
      gload16((const char*)(A + (size_t)(m0 + srow[ci])*1024 + k0) + soff[ci],
              (char*)As[buf] + (chunk0 + ci)*1024);
      gload16((const char*)(B + (size_t)(n0 + srow[ci])*1024 + k0) + soff[ci],
              (char*)Bs[buf] + (chunk0 + ci)*1024);
    }
  };

  auto COMPUTE = [&](int buf) {
#pragma unroll
    for (int kk = 0; kk < 2; ++kk) {
      s16x8 av[4], bv[4];
      const int kb = g*16 + kk*64;
#pragma unroll
      for (int m = 0; m < 4; ++m) {
        int row = wm*64 + m*16 + r;
        av[m] = *(const s16x8*)((const char*)As[buf] + row*128 + (kb ^ ((row & 7) << 4)));
      }
#pragma unroll
      for (int n = 0; n < 4; ++n) {
        int row = wn_*64 + n*16 + r;
        bv[n] = *(const s16x8*)((const char*)Bs[buf] + row*128 + (kb ^ ((row & 7) << 4)));
      }
#pragma unroll
      for (int m = 0; m < 4; ++m)
#pragma unroll
        for (int n = 0; n < 4; ++n)
          acc[m][n] = __builtin_amdgcn_mfma_f32_16x16x32_bf16(av[m], bv[n], acc[m][n], 0, 0, 0);
    }
  };

  STAGE(0, 0);
  __syncthreads();            // vmcnt(0) drain + barrier: buf0 ready
  int cur = 0;
#pragma unroll 1
  for (int t = 0; t < 15; ++t) {
    STAGE(cur ^ 1, (t + 1) * BK);   // issue next tile first: latency hides under compute
    COMPUTE(cur);
    __syncthreads();                 // drains this iter's loads; buf^1 ready
    cur ^= 1;
  }
  COMPUTE(cur);

  // ---- epilogue: +bias, ReLU, store ----
#pragma unroll
  for (int m = 0; m < 4; ++m) {
#pragma unroll
    for (int rr = 0; rr < 4; ++rr) {
      int o = m0 + wm*64 + m*16 + g*4 + rr;
      float tv = tvec[o];
      float* op = out + (size_t)o*16384 + n0 + wn_*64 + r;
#pragma unroll
      for (int n = 0; n < 4; ++n) {
        float v = acc[m][n][rr] + tv;
        op[n*16] = v > 0.f ? v : 0.f;
      }
    }
  }
}

extern "C" void kernel_launch(void* const* d_in, const int* in_sizes, int n_in,
                              void* d_out, int out_size, void* d_ws, size_t ws_size,
                              hipStream_t stream)
{
  const float* x  = (const float*)d_in[0];
  const float* sc = (const float*)d_in[1];
  const float* bi = (const float*)d_in[2];
  const float* wp = (const float*)d_in[3];
  float* out = (float*)d_out;

  char* ws = (char*)d_ws;
  float* gsum = (float*)(ws + 0);
  float* gsqs = (float*)(ws + 512);
  float* tv   = (float*)(ws + 9216);
  u16*   wn   = (u16*)(ws + 16384);
  u16*   yt   = (u16*)(ws + 2097152);

  hipMemsetAsync(ws, 0, 1024, stream);  // zero gsum+gsqs (ws is poisoned each call)
  hipLaunchKernelGGL(haar_kernel,  dim3(256, 4), dim3(256), 0, stream, x, yt, gsum, gsqs);
  hipLaunchKernelGGL(wprep_kernel, dim3(512),    dim3(256), 0, stream, wp, gsum, gsqs, sc, bi, wn, tv);
  hipLaunchKernelGGL(gemm_kernel,  dim3(512),    dim3(256), 0, stream, wn, yt, tv, out);
}